// Round 5
// baseline (81.015 us; speedup 1.0000x reference)
//
#include <hip/hip_runtime.h>
#include <cstdint>

#define BATCH 8
#define CIN 64
#define COUT 128
#define HH 32
#define WW 32

typedef int v4i __attribute__((ext_vector_type(4)));
typedef float v4f __attribute__((ext_vector_type(4)));

// ---------------- workspace layout ----------------
// byte 256: 512 x-absmax pair slots (uint64: lo=bits(max), hi=~lo)
// Self-validating: poison pattern P can never satisfy hi == ~lo.
#define PAIRS_OFF 256

// LDS tile: 3 rows x 34 px x 72 B/pixel (18 dwords: 16 data + 2 pad)
#define TPITCH 18

__device__ __forceinline__ unsigned quantb(float v, float scale) {
    float q = rintf(v * scale);
    q = fminf(fmaxf(q, -128.0f), 127.0f);
    return ((unsigned)(int)q) & 255u;
}

// =====================================================================
// SINGLE kernel: 512 blocks (b, oh, nb) x 256 threads, 2 blocks/CU
// (exactly co-resident: 2 x 256 CUs = 512). Phases:
//  0. block reduces its 1/512 x-slice (1 float4/thread, coalesced),
//     publishes partial absmax as one 8B device-scope (bits,~bits) store.
//  1. block-local w absmax (288 KB, 18 float4/thread, L2-hot) -> Tw.
//  2. spin on the 512 self-validating pair slots -> global Mx -> Tf.
//     (spin overlaps w-reduce + LDS border zero-fill; ~all partials are
//      published within ~1 us since every block runs phase 0 first)
//  3. B-quant own 64-cout w slice -> 36 KB LDS; x-halo quantize via
//     v_perm 4x4 byte transpose -> NHWC LDS tile; one barrier.
//  4. 9-tap MFMA (A and B from LDS) + scaled epilogue.
// No inter-kernel dependency, no grid.sync, no cooperative launch.
// =====================================================================
__global__ __launch_bounds__(256, 2)
void conv_all(const float* __restrict__ x, const float* __restrict__ w,
              const float* __restrict__ bias,
              const float* __restrict__ Tf_in, const float* __restrict__ Tw_in,
              unsigned long long* __restrict__ pairs, float* __restrict__ out) {
    int blk = blockIdx.x;
    int t = threadIdx.x;
    int lane = t & 63;
    int wave = t >> 6;
    int nb = blk & 1;
    int mb = blk >> 1;
    int b = mb >> 5;
    int oh = mb & 31;

    __shared__ unsigned tile[3 * 34 * TPITCH];     // 7344 B, A halo tile
    __shared__ unsigned bfrag[9 * 4 * 64 * 4];     // 36864 B, [tap][gl][ln][4dw]
    __shared__ float sm[12];

    // ---- phase 0: own x-slice absmax (1 float4/thread, exact 1/512) ----
    const float4* x4 = (const float4*)x;
    float4 xv = x4[blk * 256 + t];
    float m = fmaxf(fmaxf(fabsf(xv.x), fabsf(xv.y)), fmaxf(fabsf(xv.z), fabsf(xv.w)));

    // ---- phase 1 loads issued early: w absmax (all of w, 18 f4/thread) ----
    const float4* w4 = (const float4*)w;
    float mw0 = 0.0f, mw1 = 0.0f;
    #pragma unroll
    for (int k = 0; k < 18; k += 2) {
        float4 a = w4[t + k * 256];
        float4 c = w4[t + (k + 1) * 256];
        mw0 = fmaxf(mw0, fmaxf(fmaxf(fabsf(a.x), fabsf(a.y)), fmaxf(fabsf(a.z), fabsf(a.w))));
        mw1 = fmaxf(mw1, fmaxf(fmaxf(fabsf(c.x), fabsf(c.y)), fmaxf(fabsf(c.z), fabsf(c.w))));
    }
    float mw = fmaxf(mw0, mw1);

    #pragma unroll
    for (int off = 32; off > 0; off >>= 1) {
        m  = fmaxf(m,  __shfl_xor(m,  off, 64));
        mw = fmaxf(mw, __shfl_xor(mw, off, 64));
    }
    if (lane == 0) { sm[wave] = m; sm[4 + wave] = mw; }
    __syncthreads();
    if (t == 0) {
        float r = fmaxf(fmaxf(sm[0], sm[1]), fmaxf(sm[2], sm[3]));
        unsigned lo = __float_as_uint(r);
        unsigned long long pr = (unsigned long long)lo |
                                ((unsigned long long)(~lo) << 32);
        __hip_atomic_store(&pairs[blk], pr, __ATOMIC_RELAXED, __HIP_MEMORY_SCOPE_AGENT);
    }
    float Mw = fmaxf(fmaxf(sm[4], sm[5]), fmaxf(sm[6], sm[7]));

    // ---- LDS border zero-fill while partials propagate ----
    if (t < 96) {
        int rr = t >> 5;
        int rest = t & 31;
        int side = rest >> 4;
        int kk = rest & 15;
        tile[(rr * 34 + side * 33) * TPITCH + kk] = 0u;
    }
    if (oh == 0 || oh == 31) {
        int rbad = (oh == 0) ? 0 : 2;
        #pragma unroll
        for (int k = 0; k < 3; ++k) {
            int i = t + k * 256;
            if (i < 544) {
                int px = i >> 4, kk = i & 15;
                tile[(rbad * 34 + px) * TPITCH + kk] = 0u;
            }
        }
    }

    // ---- phase 2: spin on 512 self-validating pair slots -> Mx ----
    float mx = 0.0f;
    #pragma unroll
    for (int s2 = 0; s2 < 2; ++s2) {
        int s = t + s2 * 256;
        unsigned long long p;
        do {
            p = __hip_atomic_load(&pairs[s], __ATOMIC_RELAXED, __HIP_MEMORY_SCOPE_AGENT);
        } while ((unsigned)(p >> 32) != ~(unsigned)p);
        mx = fmaxf(mx, __uint_as_float((unsigned)p));
    }
    #pragma unroll
    for (int off = 32; off > 0; off >>= 1)
        mx = fmaxf(mx, __shfl_xor(mx, off, 64));
    if (lane == 0) sm[8 + wave] = mx;
    __syncthreads();
    float Mx = fmaxf(fmaxf(sm[8], sm[9]), fmaxf(sm[10], sm[11]));

    float Tf = 0.95f * Tf_in[0] + 0.05f * Mx;
    float Tw = 0.95f * Tw_in[0] + 0.05f * Mw;
    float scf = 127.0f / Tf;
    float scw = 127.0f / Tw;

    // ---- phase 3a: B-quant own 64-cout slice -> bfrag LDS ----
    // 1024 jobs = 4 gl-iters; job (gl, ln=t>>2, j0g=t&3):
    // 9 aligned float4 = 36 floats = 4 ci x 9 taps, contiguous per job.
    {
        int co0 = nb * 64;
        int ln = t >> 2;
        int j0g = t & 3;
        #pragma unroll
        for (int gl = 0; gl < 4; ++gl) {
            int co = co0 + gl * 16 + (ln & 15);
            int ci0 = (ln >> 4) * 16 + j0g * 4;
            int F0 = co * 576 + ci0 * 9;          // float index, %4 == 0
            float fl[36];
            #pragma unroll
            for (int r = 0; r < 9; ++r)
                *(float4*)&fl[r * 4] = w4[(F0 >> 2) + r];
            #pragma unroll
            for (int tap = 0; tap < 9; ++tap) {
                unsigned pk = quantb(fl[tap], scw)
                            | (quantb(fl[9 + tap], scw) << 8)
                            | (quantb(fl[18 + tap], scw) << 16)
                            | (quantb(fl[27 + tap], scw) << 24);
                bfrag[tap * 1024 + gl * 256 + t] = pk;
            }
        }
    }

    // ---- phase 3b: x-halo quantize + v_perm 4x4 transpose -> tile ----
    // 384 jobs: j -> (r = j>>7, wq = (j&127)>>4, g4 = j&15)
    #pragma unroll
    for (int k = 0; k < 2; ++k) {
        int j = t + k * 256;
        if (j < 384) {
            int r = j >> 7;
            int rem = j & 127;
            int wq = rem >> 4;
            int g4 = rem & 15;
            int ih = oh - 1 + r;
            if (ih >= 0 && ih < HH) {
                int xb = (b * CIN + g4 * 4) * 256 + ih * 8 + wq;
                float4 v0 = x4[xb];
                float4 v1 = x4[xb + 256];
                float4 v2 = x4[xb + 512];
                float4 v3 = x4[xb + 768];
                unsigned P0 = quantb(v0.x, scf) | (quantb(v0.y, scf) << 8) |
                              (quantb(v0.z, scf) << 16) | (quantb(v0.w, scf) << 24);
                unsigned P1 = quantb(v1.x, scf) | (quantb(v1.y, scf) << 8) |
                              (quantb(v1.z, scf) << 16) | (quantb(v1.w, scf) << 24);
                unsigned P2 = quantb(v2.x, scf) | (quantb(v2.y, scf) << 8) |
                              (quantb(v2.z, scf) << 16) | (quantb(v2.w, scf) << 24);
                unsigned P3 = quantb(v3.x, scf) | (quantb(v3.y, scf) << 8) |
                              (quantb(v3.z, scf) << 16) | (quantb(v3.w, scf) << 24);
                unsigned Q0 = __builtin_amdgcn_perm(P1, P0, 0x05040100u);
                unsigned Q1 = __builtin_amdgcn_perm(P1, P0, 0x07060302u);
                unsigned Q2 = __builtin_amdgcn_perm(P3, P2, 0x05040100u);
                unsigned Q3 = __builtin_amdgcn_perm(P3, P2, 0x07060302u);
                unsigned D0 = __builtin_amdgcn_perm(Q2, Q0, 0x06040200u);
                unsigned D1 = __builtin_amdgcn_perm(Q2, Q0, 0x07050301u);
                unsigned D2 = __builtin_amdgcn_perm(Q3, Q1, 0x06040200u);
                unsigned D3 = __builtin_amdgcn_perm(Q3, Q1, 0x07050301u);
                int base = (r * 34 + wq * 4 + 1) * TPITCH + g4;
                tile[base]              = D0;
                tile[base + TPITCH]     = D1;
                tile[base + 2 * TPITCH] = D2;
                tile[base + 3 * TPITCH] = D3;
            }
        }
    }
    __syncthreads();

    // ---- phase 4: 9-tap MFMA, A and B both from LDS ----
    int mt = wave & 1;            // pixel half (16 pixels)
    int nh2 = wave >> 1;          // cout sub-half -> gl = nh2*2 + nt
    int row = lane & 15;
    int quad = lane >> 4;
    int px0 = mt * 16 + row;

    v4i acc[2];
    acc[0] = (v4i){0, 0, 0, 0};
    acc[1] = (v4i){0, 0, 0, 0};

    const int2* tl2 = (const int2*)tile;
    const v4i* bf4 = (const v4i*)bfrag;

    #pragma unroll
    for (int tp = 0; tp < 9; ++tp) {
        const int kh = tp / 3, kw = tp % 3;
        int d = ((kh * 34) + px0 + kw) * TPITCH + quad * 4;   // even -> 8B aligned
        int2 lo = tl2[(d >> 1)];
        int2 hi = tl2[(d >> 1) + 1];
        v4i afrag = (v4i){lo.x, lo.y, hi.x, hi.y};
        #pragma unroll
        for (int nt = 0; nt < 2; ++nt) {
            int gl = nh2 * 2 + nt;
            v4i bv = bf4[(tp * 4 + gl) * 64 + lane];
            acc[nt] = __builtin_amdgcn_mfma_i32_16x16x64_i8(afrag, bv, acc[nt], 0, 0, 0);
        }
    }

    float s = (Tf / 127.0f) * (Tw / 127.0f);
    int ow0 = mt * 16 + quad * 4;
    #pragma unroll
    for (int nt = 0; nt < 2; ++nt) {
        int gl = nh2 * 2 + nt;
        int co = nb * 64 + gl * 16 + row;
        float bb = bias[co];
        v4f o;
        o.x = (float)acc[nt][0] * s + bb;
        o.y = (float)acc[nt][1] * s + bb;
        o.z = (float)acc[nt][2] * s + bb;
        o.w = (float)acc[nt][3] * s + bb;
        __builtin_nontemporal_store(o, (v4f*)(out + (((b * COUT + co) * HH + oh) * WW) + ow0));
    }
}

extern "C" void kernel_launch(void* const* d_in, const int* in_sizes, int n_in,
                              void* d_out, int out_size, void* d_ws, size_t ws_size,
                              hipStream_t stream) {
    const float* x         = (const float*)d_in[0];
    const float* weight    = (const float*)d_in[1];
    const float* bias      = (const float*)d_in[2];
    const float* T_feature = (const float*)d_in[5];
    const float* T_weight  = (const float*)d_in[6];

    unsigned long long* pairs =
        (unsigned long long*)((uint8_t*)d_ws + PAIRS_OFF);

    conv_all<<<512, 256, 0, stream>>>(x, weight, bias, T_feature, T_weight,
                                      pairs, (float*)d_out);
}

// Round 6
// 76.663 us; speedup vs baseline: 1.0568x; 1.0568x over previous
//
#include <hip/hip_runtime.h>
#include <cstdint>

#define BATCH 8
#define CIN 64
#define COUT 128
#define HH 32
#define WW 32
#define PH 34   // padded H
#define PW 34   // padded W

typedef int v4i __attribute__((ext_vector_type(4)));
typedef float v4f __attribute__((ext_vector_type(4)));

// ---------------- workspace layout ----------------
// f32[0] Tf, f32[1] Tw  (plain stores, read by conv across launch boundary)
// byte 256    : 144 absmax pair slots (uint64: lo=bits(max), hi=~lo)
//               x partials: slots 0..127, w partials: slots 128..143
// byte 4096   : xpad  int8 NHWC-padded [8,34,34,64] = 591872 B
// byte 595968 : wfrag int8 MFMA-B-swizzled [9][8][64][16] = 73728 B
#define WS_TF 0
#define WS_TW 1
#define PAIRS_OFF 256
#define XPAD_OFF 4096
#define WFRAG_OFF (4096 + BATCH * PH * PW * CIN)

__device__ __forceinline__ unsigned quantb(float v, float scale) {
    float q = rintf(v * scale);
    q = fminf(fmaxf(q, -128.0f), 127.0f);
    return ((unsigned)(int)q) & 255u;
}

// Self-validating pair: poison fill pattern P (any constant dword) can
// never satisfy hi == ~lo, so consumers spin until the fresh value lands.
__device__ __forceinline__ void pair_publish(unsigned long long* slot, float v) {
    unsigned lo = __float_as_uint(v);
    unsigned long long pr = (unsigned long long)lo |
                            ((unsigned long long)(~lo) << 32);
    __hip_atomic_store(slot, pr, __ATOMIC_RELAXED, __HIP_MEMORY_SCOPE_AGENT);
}
__device__ __forceinline__ float pair_wait(const unsigned long long* slot) {
    unsigned long long p;
    do {
        p = __hip_atomic_load(slot, __ATOMIC_RELAXED, __HIP_MEMORY_SCOPE_AGENT);
    } while ((unsigned)(p >> 32) != ~(unsigned)p);
    return __uint_as_float((unsigned)p);
}

// =====================================================================
// kernel 1: absmax + zfill + quantize/pack, fused via pair-slot spin.
// blocks   0..127 : x absmax partials -> pair slots 0..127   (producers)
// blocks 128..143 : w absmax partials -> pair slots 128..143 (producers)
// blocks 144..209 : xpad border zero-fill (independent)
// blocks 210..465 : x quantize + LDS transpose + NHWC pack (spin on 0..127)
// blocks 466..537 : w quantize -> MFMA-B fragments (spin on 128..143)
// 538 blocks of 4 waves each co-reside easily (capacity ~2048): producers
// always run, consumers prefetch their loads BEFORE spinning.
// =====================================================================
__global__ __launch_bounds__(256) void prep_all(const float* __restrict__ x,
                                                const float* __restrict__ w,
                                                const float* __restrict__ Tf_in,
                                                const float* __restrict__ Tw_in,
                                                float* __restrict__ ws_f32,
                                                unsigned long long* __restrict__ pairs,
                                                uint8_t* __restrict__ xpad,
                                                uint8_t* __restrict__ wfrag) {
    int blk = blockIdx.x;
    int t = threadIdx.x;
    int lane = t & 63;
    int wave = t >> 6;
    __shared__ float sm[4];
    __shared__ unsigned lds[CIN * 9];   // x-pack transpose buffer (pitch 9)

    if (blk < 144) {
        // ---- producers: absmax partials (R0 coverage, exact) ----
        float m = 0.0f;
        if (blk < 128) {
            const float4* p = (const float4*)x;
            int base = blk * 1024 + t;
            #pragma unroll
            for (int k = 0; k < 4; ++k) {
                float4 v = p[base + k * 256];
                m = fmaxf(m, fmaxf(fmaxf(fabsf(v.x), fabsf(v.y)),
                                   fmaxf(fabsf(v.z), fabsf(v.w))));
            }
        } else {
            const float4* p = (const float4*)w;
            int wb = blk - 128;
            int base = wb * 1152 + t;
            int end = (wb + 1) * 1152;
            #pragma unroll
            for (int k = 0; k < 5; ++k) {
                int i = base + k * 256;
                if (i < end) {
                    float4 v = p[i];
                    m = fmaxf(m, fmaxf(fmaxf(fabsf(v.x), fabsf(v.y)),
                                       fmaxf(fabsf(v.z), fabsf(v.w))));
                }
            }
        }
        #pragma unroll
        for (int off = 32; off > 0; off >>= 1)
            m = fmaxf(m, __shfl_xor(m, off, 64));
        if ((t & 63) == 0) sm[wave] = m;
        __syncthreads();
        if (t == 0)
            pair_publish(&pairs[blk],
                         fmaxf(fmaxf(sm[0], sm[1]), fmaxf(sm[2], sm[3])));
        return;
    }

    if (blk < 210) {
        // ---- xpad border zero-fill: 1056 px * 16 dwords ----
        int j = (blk - 144) * 256 + t;
        int p = j >> 4, c4 = j & 15;
        int b = p / 132;
        int r = p - b * 132;
        int ih, iw;
        if (r < 34)      { ih = 0;           iw = r; }
        else if (r < 68) { ih = PH - 1;      iw = r - 34; }
        else if (r < 100){ ih = r - 68 + 1;  iw = 0; }
        else             { ih = r - 100 + 1; iw = PW - 1; }
        ((unsigned*)xpad)[((b * PH + ih) * PW + iw) * 16 + c4] = 0u;
        return;
    }

    if (blk < 466) {
        // ---- x-pack consumers: prefetch BOTH float4 before the spin ----
        int xb = blk - 210;
        int b = xb >> 5, h = xb & 31;
        const float4* x4 = (const float4*)x;
        int ci0 = t >> 3, wq = t & 7;
        int ci1 = (t + 256) >> 3;           // wq identical (256 % 8 == 0)
        float4 va = x4[(b * CIN + ci0) * 256 + h * 8 + wq];
        float4 vb = x4[(b * CIN + ci1) * 256 + h * 8 + wq];

        float m = fmaxf(pair_wait(&pairs[lane]), pair_wait(&pairs[64 + lane]));
        #pragma unroll
        for (int off = 32; off > 0; off >>= 1)
            m = fmaxf(m, __shfl_xor(m, off, 64));
        float Tf = 0.95f * Tf_in[0] + 0.05f * m;
        if (blk == 210 && t == 0) ws_f32[WS_TF] = Tf;
        float scale = 127.0f / Tf;

        lds[ci0 * 9 + wq] = quantb(va.x, scale) | (quantb(va.y, scale) << 8) |
                            (quantb(va.z, scale) << 16) | (quantb(va.w, scale) << 24);
        lds[ci1 * 9 + wq] = quantb(vb.x, scale) | (quantb(vb.y, scale) << 8) |
                            (quantb(vb.z, scale) << 16) | (quantb(vb.w, scale) << 24);
        __syncthreads();
        const uint8_t* ldsb = (const uint8_t*)lds;
        unsigned* orow = (unsigned*)(xpad + (((b * PH) + (h + 1)) * PW + 1) * CIN);
        #pragma unroll
        for (int k = 0; k < 2; ++k) {
            int o = t + k * 256;            // [0,512): w = o>>4, c4 = o&15
            int ww_ = o >> 4, c4 = o & 15;
            unsigned d = (unsigned)ldsb[(c4 * 4 + 0) * 36 + ww_]
                       | ((unsigned)ldsb[(c4 * 4 + 1) * 36 + ww_] << 8)
                       | ((unsigned)ldsb[(c4 * 4 + 2) * 36 + ww_] << 16)
                       | ((unsigned)ldsb[(c4 * 4 + 3) * 36 + ww_] << 24);
            orow[o] = d;
        }
        return;
    }

    // ---- w-pack consumers: prefetch 4 scalars before the spin ----
    {
        int tid = (blk - 466) * 256 + t;
        int idx4 = tid * 4;
        int j0 = idx4 & 15;
        int ln = (idx4 >> 4) & 63;
        int f  = idx4 >> 10;          // tap*8 + g
        int g = f & 7;
        int tap = f >> 3;
        int kh = tap / 3, kw = tap - kh * 3;
        int co = g * 16 + (ln & 15);
        int ci0 = (ln >> 4) * 16 + j0;
        float fv[4];
        #pragma unroll
        for (int c = 0; c < 4; ++c)
            fv[c] = w[((co * CIN + ci0 + c) * 3 + kh) * 3 + kw];

        float pw = pair_wait(&pairs[128 + (lane & 15)]);
        #pragma unroll
        for (int off = 32; off > 0; off >>= 1)
            pw = fmaxf(pw, __shfl_xor(pw, off, 64));
        float Tw = 0.95f * Tw_in[0] + 0.05f * pw;
        if (blk == 466 && t == 0) ws_f32[WS_TW] = Tw;
        float scale = 127.0f / Tw;

        unsigned pack = 0;
        #pragma unroll
        for (int c = 0; c < 4; ++c)
            pack |= quantb(fv[c], scale) << (8 * c);
        ((unsigned*)wfrag)[tid] = pack;
    }
}

// ---------- kernel 2: implicit-GEMM conv, R0-verbatim (proven) ----------
__global__ __launch_bounds__(256, 2) void conv_mfma(const uint8_t* __restrict__ xpad,
                                                    const uint8_t* __restrict__ wfrag,
                                                    const float* __restrict__ bias,
                                                    const float* __restrict__ ws_f32,
                                                    float* __restrict__ out) {
    int blk = blockIdx.x;         // 512: nb = blk&1 (cout half), mb = blk>>1
    int nb = blk & 1;
    int mb = blk >> 1;
    int b = mb >> 5;
    int oh = mb & 31;
    int wave = threadIdx.x >> 6;
    int lane = threadIdx.x & 63;
    int mt = wave & 1;            // pixel half (16 pixels)
    int nh2 = wave >> 1;          // cout sub-half
    int row = lane & 15;
    int quad = lane >> 4;

    v4i acc[2];
    acc[0] = (v4i){0, 0, 0, 0};
    acc[1] = (v4i){0, 0, 0, 0};

    const uint8_t* xbase = xpad + (((b * PH + oh) * PW) + mt * 16 + row) * CIN + quad * 16;

    #pragma unroll
    for (int tp = 0; tp < 9; ++tp) {
        const int kh = tp / 3, kw = tp % 3;
        v4i afrag = *(const v4i*)(xbase + (kh * PW + kw) * CIN);
        #pragma unroll
        for (int nt = 0; nt < 2; ++nt) {
            int g = nb * 4 + nh2 * 2 + nt;
            v4i bfrag = *(const v4i*)(wfrag + (((tp * 8 + g) * 64) + lane) * 16);
            acc[nt] = __builtin_amdgcn_mfma_i32_16x16x64_i8(afrag, bfrag, acc[nt], 0, 0, 0);
        }
    }

    float Tf = ws_f32[WS_TF];
    float Tw = ws_f32[WS_TW];
    float s = (Tf / 127.0f) * (Tw / 127.0f);
    int ow0 = mt * 16 + quad * 4;
    #pragma unroll
    for (int nt = 0; nt < 2; ++nt) {
        int g = nb * 4 + nh2 * 2 + nt;
        int co = g * 16 + row;
        float bb = bias[co];
        v4f o;
        o.x = (float)acc[nt][0] * s + bb;
        o.y = (float)acc[nt][1] * s + bb;
        o.z = (float)acc[nt][2] * s + bb;
        o.w = (float)acc[nt][3] * s + bb;
        __builtin_nontemporal_store(o, (v4f*)(out + (((b * COUT + co) * HH + oh) * WW) + ow0));
    }
}

extern "C" void kernel_launch(void* const* d_in, const int* in_sizes, int n_in,
                              void* d_out, int out_size, void* d_ws, size_t ws_size,
                              hipStream_t stream) {
    const float* x         = (const float*)d_in[0];
    const float* weight    = (const float*)d_in[1];
    const float* bias      = (const float*)d_in[2];
    const float* T_feature = (const float*)d_in[5];
    const float* T_weight  = (const float*)d_in[6];

    float*              ws_f32 = (float*)d_ws;
    unsigned long long* pairs  = (unsigned long long*)((uint8_t*)d_ws + PAIRS_OFF);
    uint8_t*            xpad   = (uint8_t*)d_ws + XPAD_OFF;
    uint8_t*            wfrag  = (uint8_t*)d_ws + WFRAG_OFF;

    prep_all<<<538, 256, 0, stream>>>(x, weight, T_feature, T_weight,
                                      ws_f32, pairs, xpad, wfrag);
    conv_mfma<<<512, 256, 0, stream>>>(xpad, wfrag, bias, ws_f32, (float*)d_out);
}

// Round 7
// 75.546 us; speedup vs baseline: 1.0724x; 1.0148x over previous
//
#include <hip/hip_runtime.h>
#include <cstdint>

#define BATCH 8
#define CIN 64
#define COUT 128
#define HH 32
#define WW 32
#define PH 34   // padded H
#define PW 34   // padded W

typedef int v4i __attribute__((ext_vector_type(4)));
typedef float v4f __attribute__((ext_vector_type(4)));

// ---------------- workspace layout ----------------
// f32[0] Tf, f32[1] Tw, f32[16..175] partials (x: 16..143, w: 144..159)
// byte 4096   : xpad  int8 NHWC-padded [8,34,34,64] = 591872 B
// byte 595968 : wfrag int8 MFMA-B-swizzled [9][8][64][16] = 73728 B
#define WS_TF 0
#define WS_TW 1
#define WS_PART 16
#define XPAD_OFF 4096
#define WFRAG_OFF (4096 + BATCH * PH * PW * CIN)

// ---------- kernel 1: absmax partials + xpad border zero-fill ----------
// blocks 0..127  : x absmax partials
// blocks 128..143: w absmax partials
// blocks 144..209: xpad border zero-fill (independent of absmax)
__global__ __launch_bounds__(256) void absmax_zfill(const float* __restrict__ x,
                                                    const float* __restrict__ w,
                                                    float* __restrict__ partials,
                                                    uint8_t* __restrict__ xpad) {
    int blk = blockIdx.x;
    int t = threadIdx.x;

    if (blk >= 144) {
        // ---- border zero-fill: 1056 pixels * 16 dwords = 16896 dwords ----
        int j = (blk - 144) * 256 + t;
        int p = j >> 4, c4 = j & 15;
        int b = p / 132;
        int r = p - b * 132;
        int ih, iw;
        if (r < 34)      { ih = 0;           iw = r; }
        else if (r < 68) { ih = PH - 1;      iw = r - 34; }
        else if (r < 100){ ih = r - 68 + 1;  iw = 0; }
        else             { ih = r - 100 + 1; iw = PW - 1; }
        ((unsigned*)xpad)[((b * PH + ih) * PW + iw) * 16 + c4] = 0u;
        return;
    }

    float m = 0.0f;
    if (blk < 128) {
        const float4* p = (const float4*)x;
        int base = blk * 1024 + t;
        #pragma unroll
        for (int k = 0; k < 4; ++k) {
            float4 v = p[base + k * 256];
            m = fmaxf(m, fmaxf(fmaxf(fabsf(v.x), fabsf(v.y)), fmaxf(fabsf(v.z), fabsf(v.w))));
        }
    } else {
        const float4* p = (const float4*)w;
        int wb = blk - 128;
        int base = wb * 1152 + t;
        int end = (wb + 1) * 1152;
        #pragma unroll
        for (int k = 0; k < 5; ++k) {
            int i = base + k * 256;
            if (i < end) {
                float4 v = p[i];
                m = fmaxf(m, fmaxf(fmaxf(fabsf(v.x), fabsf(v.y)), fmaxf(fabsf(v.z), fabsf(v.w))));
            }
        }
    }
    #pragma unroll
    for (int off = 32; off > 0; off >>= 1)
        m = fmaxf(m, __shfl_xor(m, off, 64));
    __shared__ float sm[4];
    int wave = t >> 6;
    if ((t & 63) == 0) sm[wave] = m;
    __syncthreads();
    if (t == 0)
        partials[WS_PART + blk] = fmaxf(fmaxf(sm[0], sm[1]), fmaxf(sm[2], sm[3]));
}

__device__ __forceinline__ unsigned quantb(float v, float scale) {
    float q = rintf(v * scale);
    q = fminf(fmaxf(q, -128.0f), 127.0f);
    return ((unsigned)(int)q) & 255u;
}

// ---------- kernel 2: fused quantize+pack (x interior + weights) ----------
#define QB_X 256
#define QB_W 72
__global__ __launch_bounds__(256) void quant_pack(const float* __restrict__ x,
                                                  const float* __restrict__ w,
                                                  const float* __restrict__ Tf_in,
                                                  const float* __restrict__ Tw_in,
                                                  float* __restrict__ ws_f32,
                                                  uint8_t* __restrict__ xpad,
                                                  uint8_t* __restrict__ wfrag) {
    int blk = blockIdx.x;
    int t = threadIdx.x;
    int lane = t & 63;

    if (blk < QB_X) {
        // ---- x rows: coalesced float4 read, quantize, LDS transpose, NHWC write ----
        float m = fmaxf(ws_f32[WS_PART + lane], ws_f32[WS_PART + 64 + lane]);
        #pragma unroll
        for (int off = 32; off > 0; off >>= 1)
            m = fmaxf(m, __shfl_xor(m, off, 64));
        float a = 0.95f * Tf_in[0];
        float bt = 0.05f * m;
        float Tf = a + bt;
        if (blk == 0 && t == 0) ws_f32[WS_TF] = Tf;
        float scale = 127.0f / Tf;

        int b = blk >> 5, h = blk & 31;
        const float4* x4 = (const float4*)x;
        __shared__ unsigned lds[CIN * 9];   // pitch 9 dwords per ci
        #pragma unroll
        for (int k = 0; k < 2; ++k) {
            int f = t + k * 256;            // [0,512): ci = f>>3, wq = f&7
            int ci = f >> 3, wq = f & 7;
            float4 v = x4[(b * CIN + ci) * 256 + h * 8 + wq];
            unsigned pack = quantb(v.x, scale) | (quantb(v.y, scale) << 8) |
                            (quantb(v.z, scale) << 16) | (quantb(v.w, scale) << 24);
            lds[ci * 9 + wq] = pack;
        }
        __syncthreads();
        const uint8_t* ldsb = (const uint8_t*)lds;
        unsigned* orow = (unsigned*)(xpad + (((b * PH) + (h + 1)) * PW + 1) * CIN);
        #pragma unroll
        for (int k = 0; k < 2; ++k) {
            int o = t + k * 256;            // [0,512): w = o>>4, c4 = o&15
            int ww_ = o >> 4, c4 = o & 15;
            unsigned d = (unsigned)ldsb[(c4 * 4 + 0) * 36 + ww_]
                       | ((unsigned)ldsb[(c4 * 4 + 1) * 36 + ww_] << 8)
                       | ((unsigned)ldsb[(c4 * 4 + 2) * 36 + ww_] << 16)
                       | ((unsigned)ldsb[(c4 * 4 + 3) * 36 + ww_] << 24);
            orow[o] = d;
        }
    } else {
        // ---- weights -> MFMA-B fragment order ----
        float m = ws_f32[WS_PART + 128 + (lane & 15)];
        #pragma unroll
        for (int off = 32; off > 0; off >>= 1)
            m = fmaxf(m, __shfl_xor(m, off, 64));
        float a = 0.95f * Tw_in[0];
        float bt = 0.05f * m;
        float Tw = a + bt;
        if (blk == QB_X && t == 0) ws_f32[WS_TW] = Tw;
        float scale = 127.0f / Tw;

        int tid = (blk - QB_X) * 256 + t;
        int idx4 = tid * 4;
        int j0 = idx4 & 15;
        int ln = (idx4 >> 4) & 63;
        int f  = idx4 >> 10;          // tap*8 + g
        int g = f & 7;
        int tap = f >> 3;
        int kh = tap / 3, kw = tap - kh * 3;
        int co = g * 16 + (ln & 15);
        int ci0 = (ln >> 4) * 16 + j0;
        unsigned pack = 0;
        #pragma unroll
        for (int c = 0; c < 4; ++c) {
            float v = w[((co * CIN + ci0 + c) * 3 + kh) * 3 + kw];
            pack |= quantb(v, scale) << (8 * c);
        }
        ((unsigned*)wfrag)[tid] = pack;
    }
}

// ---------- kernel 3: implicit-GEMM conv, 512 blocks (2/CU) ----------
__global__ __launch_bounds__(256, 2) void conv_mfma(const uint8_t* __restrict__ xpad,
                                                    const uint8_t* __restrict__ wfrag,
                                                    const float* __restrict__ bias,
                                                    const float* __restrict__ ws_f32,
                                                    float* __restrict__ out) {
    int blk = blockIdx.x;         // 512: nb = blk&1 (cout half), mb = blk>>1
    int nb = blk & 1;
    int mb = blk >> 1;
    int b = mb >> 5;
    int oh = mb & 31;
    int wave = threadIdx.x >> 6;
    int lane = threadIdx.x & 63;
    int mt = wave & 1;            // pixel half (16 pixels)
    int nh2 = wave >> 1;          // cout sub-half
    int row = lane & 15;
    int quad = lane >> 4;

    v4i acc[2];
    acc[0] = (v4i){0, 0, 0, 0};
    acc[1] = (v4i){0, 0, 0, 0};

    const uint8_t* xbase = xpad + (((b * PH + oh) * PW) + mt * 16 + row) * CIN + quad * 16;

    #pragma unroll
    for (int tp = 0; tp < 9; ++tp) {
        const int kh = tp / 3, kw = tp % 3;
        v4i afrag = *(const v4i*)(xbase + (kh * PW + kw) * CIN);
        #pragma unroll
        for (int nt = 0; nt < 2; ++nt) {
            int g = nb * 4 + nh2 * 2 + nt;
            v4i bfrag = *(const v4i*)(wfrag + (((tp * 8 + g) * 64) + lane) * 16);
            acc[nt] = __builtin_amdgcn_mfma_i32_16x16x64_i8(afrag, bfrag, acc[nt], 0, 0, 0);
        }
    }

    float Tf = ws_f32[WS_TF];
    float Tw = ws_f32[WS_TW];
    float s = (Tf / 127.0f) * (Tw / 127.0f);
    int ow0 = mt * 16 + quad * 4;
    #pragma unroll
    for (int nt = 0; nt < 2; ++nt) {
        int g = nb * 4 + nh2 * 2 + nt;
        int co = g * 16 + row;
        float bb = bias[co];
        v4f o;
        o.x = (float)acc[nt][0] * s + bb;
        o.y = (float)acc[nt][1] * s + bb;
        o.z = (float)acc[nt][2] * s + bb;
        o.w = (float)acc[nt][3] * s + bb;
        __builtin_nontemporal_store(o, (v4f*)(out + (((b * COUT + co) * HH + oh) * WW) + ow0));
    }
}

extern "C" void kernel_launch(void* const* d_in, const int* in_sizes, int n_in,
                              void* d_out, int out_size, void* d_ws, size_t ws_size,
                              hipStream_t stream) {
    const float* x         = (const float*)d_in[0];
    const float* weight    = (const float*)d_in[1];
    const float* bias      = (const float*)d_in[2];
    const float* T_feature = (const float*)d_in[5];
    const float* T_weight  = (const float*)d_in[6];

    float*   ws_f32 = (float*)d_ws;
    uint8_t* xpad   = (uint8_t*)d_ws + XPAD_OFF;
    uint8_t* wfrag  = (uint8_t*)d_ws + WFRAG_OFF;

    absmax_zfill<<<210, 256, 0, stream>>>(x, weight, ws_f32, xpad);
    quant_pack<<<QB_X + QB_W, 256, 0, stream>>>(x, weight, T_feature, T_weight,
                                                ws_f32, xpad, wfrag);
    conv_mfma<<<512, 256, 0, stream>>>(xpad, wfrag, bias, ws_f32, (float*)d_out);
}